// Round 1
// baseline (876.873 us; speedup 1.0000x reference)
//
#include <hip/hip_runtime.h>

typedef __attribute__((ext_vector_type(8))) short bf16x8;
typedef __attribute__((ext_vector_type(4))) float f32x4;
typedef __attribute__((ext_vector_type(4))) float f4v;

__device__ __forceinline__ unsigned short f2bf(float f){
  unsigned u = __builtin_bit_cast(unsigned, f);
  u += 0x7FFFu + ((u >> 16) & 1u);
  return (unsigned short)(u >> 16);
}
__device__ __forceinline__ float bf2f(unsigned short b){
  unsigned u = ((unsigned)b) << 16;
  return __builtin_bit_cast(float, u);
}
__device__ __forceinline__ float sigmoidf_(float x){ return 1.f/(1.f + __expf(-x)); }
__device__ __forceinline__ float tanhf_(float x){
  float a = fabsf(x);
  float t = __expf(-2.f*a);
  float r = (1.f - t)/(1.f + t);
  return copysignf(r, x);
}

struct WF { bf16x8 hi, lo; };

// split-precision accumulate: hi-chain gets ah*Bhi, lo-chain gets al*Bhi + ah*Blo
__device__ __forceinline__ void mmsplit(bf16x8 ah, bf16x8 al, const WF& B,
                                        f32x4& Dh, f32x4& Dl){
  Dh = __builtin_amdgcn_mfma_f32_16x16x32_bf16(ah, B.hi, Dh, 0, 0, 0);
  Dl = __builtin_amdgcn_mfma_f32_16x16x32_bf16(al, B.hi, Dl, 0, 0, 0);
  Dl = __builtin_amdgcn_mfma_f32_16x16x32_bf16(ah, B.lo, Dl, 0, 0, 0);
}

__device__ __forceinline__ WF load_wf(const float* W, int ldk, int row, int k0, int kmax){
  WF f;
  #pragma unroll
  for (int j = 0; j < 8; j++){
    int k = k0 + j;
    float v = (k < kmax) ? W[row*ldk + k] : 0.f;
    unsigned short hb = f2bf(v);
    f.hi[j] = (short)hb;
    f.lo[j] = (short)f2bf(v - bf2f(hb));
  }
  return f;
}

// ---------------- GRU: 2 layers fused, 16 nodes per WG, 1 barrier/step ----------------
__global__ __launch_bounds__(256, 1)
void gru_kernel(const float* __restrict__ x,
                const float* __restrict__ Wih0, const float* __restrict__ Whh0,
                const float* __restrict__ bih0, const float* __restrict__ bhh0,
                const float* __restrict__ Wih1, const float* __restrict__ Whh1,
                const float* __restrict__ bih1, const float* __restrict__ bhh1,
                float* __restrict__ hfin){
  __shared__ unsigned short xp_hi[16][60][8];
  __shared__ unsigned short xp_lo[16][60][8];
  __shared__ unsigned short h0hi[2][16][72], h0lo[2][16][72];
  __shared__ unsigned short h1hi[2][16][72], h1lo[2][16][72];

  const int tid  = threadIdx.x;
  const int lane = tid & 63;
  const int w    = tid >> 6;
  const int c    = lane & 15;
  const int q    = lane >> 4;
  const int d    = w*16 + c;
  const int nbase = blockIdx.x * 16;

  for (int v = tid; v < 16*360; v += 256){
    int n = v / 360, rem = v % 360;
    int dd = rem / 60, tt = rem % 60;
    float f = x[(size_t)(nbase + n)*360 + rem];
    unsigned short hb = f2bf(f);
    xp_hi[n][tt][dd] = hb;
    xp_lo[n][tt][dd] = f2bf(f - bf2f(hb));
  }
  for (int v = tid; v < 16*60*2; v += 256){
    int n = v / 120, rem = v % 120;
    int tt = rem >> 1, dd = 6 + (rem & 1);
    xp_hi[n][tt][dd] = 0; xp_lo[n][tt][dd] = 0;
  }
  for (int v = tid; v < 2*16*72; v += 256){
    ((unsigned short*)h0hi)[v] = 0; ((unsigned short*)h0lo)[v] = 0;
    ((unsigned short*)h1hi)[v] = 0; ((unsigned short*)h1lo)[v] = 0;
  }

  const float bi0r = bih0[d], bi0z = bih0[64+d], bi0n = bih0[128+d];
  const float bh0r = bhh0[d], bh0z = bhh0[64+d], bh0n = bhh0[128+d];
  const float bi1r = bih1[d], bi1z = bih1[64+d], bi1n = bih1[128+d];
  const float bh1r = bhh1[d], bh1z = bhh1[64+d], bh1n = bhh1[128+d];

  WF Bih0[3];
  WF Bhh0[3][2], Bih1[3][2], Bhh1[3][2];
  #pragma unroll
  for (int g = 0; g < 3; g++){
    int row = g*64 + d;
    Bih0[g] = load_wf(Wih0, 6, row, q*8, 6);
    #pragma unroll
    for (int kt = 0; kt < 2; kt++){
      Bhh0[g][kt] = load_wf(Whh0, 64, row, kt*32 + q*8, 64);
      Bih1[g][kt] = load_wf(Wih1, 64, row, kt*32 + q*8, 64);
      Bhh1[g][kt] = load_wf(Whh1, 64, row, kt*32 + q*8, 64);
    }
  }

  float h0old[4] = {0,0,0,0}, h1old[4] = {0,0,0,0};

  __syncthreads();

  #pragma unroll 1
  for (int t = 0; t < 60; t++){
    const int p  = t & 1;
    const int qb = p ^ 1;

    // ---- layer 0: reads h0[p] (state), writes h0[qb] ----
    bf16x8 a_h0h[2], a_h0l[2];
    #pragma unroll
    for (int kt = 0; kt < 2; kt++){
      a_h0h[kt] = *(const bf16x8*)&h0hi[p][c][kt*32 + q*8];
      a_h0l[kt] = *(const bf16x8*)&h0lo[p][c][kt*32 + q*8];
    }
    bf16x8 a_xh = {}, a_xl = {};
    if (q == 0){
      a_xh = *(const bf16x8*)&xp_hi[c][t][0];
      a_xl = *(const bf16x8*)&xp_lo[c][t][0];
    }

    f32x4 RH = {0,0,0,0}, RL = {0,0,0,0};
    f32x4 ZH = {0,0,0,0}, ZL = {0,0,0,0};
    f32x4 NIH = {0,0,0,0}, NIL = {0,0,0,0};
    f32x4 NHH = {0,0,0,0}, NHL = {0,0,0,0};
    mmsplit(a_xh, a_xl, Bih0[0], RH, RL);
    mmsplit(a_xh, a_xl, Bih0[1], ZH, ZL);
    mmsplit(a_xh, a_xl, Bih0[2], NIH, NIL);
    #pragma unroll
    for (int kt = 0; kt < 2; kt++){
      mmsplit(a_h0h[kt], a_h0l[kt], Bhh0[0][kt], RH, RL);
      mmsplit(a_h0h[kt], a_h0l[kt], Bhh0[1][kt], ZH, ZL);
      mmsplit(a_h0h[kt], a_h0l[kt], Bhh0[2][kt], NHH, NHL);
    }
    #pragma unroll
    for (int rI = 0; rI < 4; rI++){
      float rv = sigmoidf_(RH[rI] + RL[rI] + bi0r + bh0r);
      float zv = sigmoidf_(ZH[rI] + ZL[rI] + bi0z + bh0z);
      float nv = tanhf_(NIH[rI] + NIL[rI] + bi0n + rv*(NHH[rI] + NHL[rI] + bh0n));
      float hnew = (1.f - zv)*nv + zv*h0old[rI];
      h0old[rI] = hnew;
      unsigned short hb = f2bf(hnew);
      int node = q*4 + rI;
      h0hi[qb][node][d] = hb;
      h0lo[qb][node][d] = f2bf(hnew - bf2f(hb));
    }
    __syncthreads();   // the ONLY barrier per step

    // ---- layer 1: reads h0[qb] (y1_t) and h1[p] (state), writes h1[qb] ----
    bf16x8 a_yh[2], a_yl[2], a_h1h[2], a_h1l[2];
    #pragma unroll
    for (int kt = 0; kt < 2; kt++){
      a_yh[kt]  = *(const bf16x8*)&h0hi[qb][c][kt*32 + q*8];
      a_yl[kt]  = *(const bf16x8*)&h0lo[qb][c][kt*32 + q*8];
      a_h1h[kt] = *(const bf16x8*)&h1hi[p][c][kt*32 + q*8];
      a_h1l[kt] = *(const bf16x8*)&h1lo[p][c][kt*32 + q*8];
    }
    f32x4 EH = {0,0,0,0}, EL = {0,0,0,0};
    f32x4 FH = {0,0,0,0}, FL = {0,0,0,0};
    f32x4 GIH = {0,0,0,0}, GIL = {0,0,0,0};
    f32x4 GHH = {0,0,0,0}, GHL = {0,0,0,0};
    #pragma unroll
    for (int kt = 0; kt < 2; kt++){
      mmsplit(a_yh[kt], a_yl[kt], Bih1[0][kt], EH, EL);
      mmsplit(a_yh[kt], a_yl[kt], Bih1[1][kt], FH, FL);
      mmsplit(a_yh[kt], a_yl[kt], Bih1[2][kt], GIH, GIL);
      mmsplit(a_h1h[kt], a_h1l[kt], Bhh1[0][kt], EH, EL);
      mmsplit(a_h1h[kt], a_h1l[kt], Bhh1[1][kt], FH, FL);
      mmsplit(a_h1h[kt], a_h1l[kt], Bhh1[2][kt], GHH, GHL);
    }
    #pragma unroll
    for (int rI = 0; rI < 4; rI++){
      float rv = sigmoidf_(EH[rI] + EL[rI] + bi1r + bh1r);
      float zv = sigmoidf_(FH[rI] + FL[rI] + bi1z + bh1z);
      float nv = tanhf_(GIH[rI] + GIL[rI] + bi1n + rv*(GHH[rI] + GHL[rI] + bh1n));
      float hnew = (1.f - zv)*nv + zv*h1old[rI];
      h1old[rI] = hnew;
      unsigned short hb = f2bf(hnew);
      int node = q*4 + rI;
      h1hi[qb][node][d] = hb;
      h1lo[qb][node][d] = f2bf(hnew - bf2f(hb));
    }
    // no end-of-step barrier: next step's pre-barrier reads touch only
    // buffers written before this step's barrier; h1[qb] is read next step
    // only after next step's barrier.
  }

  #pragma unroll
  for (int rI = 0; rI < 4; rI++){
    int node = nbase + q*4 + rI;
    hfin[(size_t)node*64 + d] = h1old[rI];
  }
}

// ---------------- a,c per head: a=h@W[:64], c=h@W[64:] ----------------
__global__ void ac_kernel(const float* __restrict__ hfin,
                          const float* __restrict__ W0h, const float* __restrict__ W1h,
                          const float* __restrict__ W2h, float* __restrict__ ac){
  int lane = threadIdx.x & 63;
  int node = blockIdx.x*4 + (threadIdx.x >> 6);
  float hv = hfin[(size_t)node*64 + lane];
  const float* Ws[3] = {W0h, W1h, W2h};
  #pragma unroll
  for (int h = 0; h < 3; h++){
    float pa = hv * Ws[h][lane];
    float pc = hv * Ws[h][64 + lane];
    #pragma unroll
    for (int m = 32; m >= 1; m >>= 1){
      pa += __shfl_xor(pa, m, 64);
      pc += __shfl_xor(pc, m, 64);
    }
    if (lane == 0){
      ac[(size_t)(2*h)*4000 + node]   = pa;
      ac[(size_t)(2*h+1)*4000 + node] = pc;
    }
  }
}

// -------- fused 3-head masked softmax (no max pass) + aggregation + fc --------
// 2 rows per WG, 2000 WGs, register-prefetched rel stream.
__global__ __launch_bounds__(256, 3)
void attn2_kernel(const float* __restrict__ rel, const float* __restrict__ hfin,
                  const float* __restrict__ ac,
                  const float* __restrict__ b0p, const float* __restrict__ b1p,
                  const float* __restrict__ b2p,
                  const float* __restrict__ fcw, const float* __restrict__ fcb,
                  float* __restrict__ pred){
  __shared__ float m0[4000], m1[4000];     // mask, then combined weight
  __shared__ float red[4][8];

  const int tid  = threadIdx.x;
  const int lane = tid & 63;
  const int w    = tid >> 6;
  const int i0   = blockIdx.x * 2;
  const float bh[3] = {b0p[0], b1p[0], b2p[0]};

  const float* c0 = ac + 1*4000;
  const float* c1 = ac + 3*4000;
  const float* c2 = ac + 5*4000;

  float ai[2][3];
  #pragma unroll
  for (int r = 0; r < 2; r++)
    #pragma unroll
    for (int h = 0; h < 3; h++)
      ai[r][h] = ac[(size_t)(2*h)*4000 + i0 + r];

  float z[2][3] = {{0.f,0.f,0.f},{0.f,0.f,0.f}};

  // Pass A: stream rel once with register prefetch; masks -> LDS; Z accum (no max)
  {
    int j = tid;
    bool have = (j < 4000);
    f4v r0, r1, r2, r3;
    if (have){
      const f4v* rp0 = (const f4v*)(rel + ((size_t)i0*4000 + j)*8);
      const f4v* rp1 = (const f4v*)(rel + ((size_t)(i0+1)*4000 + j)*8);
      r0 = __builtin_nontemporal_load(rp0);
      r1 = __builtin_nontemporal_load(rp0 + 1);
      r2 = __builtin_nontemporal_load(rp1);
      r3 = __builtin_nontemporal_load(rp1 + 1);
    }
    while (have){
      int jn = j + 256;
      bool haven = (jn < 4000);
      f4v n0, n1, n2, n3;
      if (haven){
        const f4v* rp0 = (const f4v*)(rel + ((size_t)i0*4000 + jn)*8);
        const f4v* rp1 = (const f4v*)(rel + ((size_t)(i0+1)*4000 + jn)*8);
        n0 = __builtin_nontemporal_load(rp0);
        n1 = __builtin_nontemporal_load(rp0 + 1);
        n2 = __builtin_nontemporal_load(rp1);
        n3 = __builtin_nontemporal_load(rp1 + 1);
      }
      float mk0 = r0[0]+r0[1]+r0[2]+r0[3] + r1[0]+r1[1]+r1[2]+r1[3];
      float mk1 = r2[0]+r2[1]+r2[2]+r2[3] + r3[0]+r3[1]+r3[2]+r3[3];
      m0[j] = mk0; m1[j] = mk1;
      float cv[3] = {c0[j], c1[j], c2[j]};
      #pragma unroll
      for (int h = 0; h < 3; h++){
        float s0 = ai[0][h] + cv[h] + bh[h];
        float s1 = ai[1][h] + cv[h] + bh[h];
        float w0 = s0 > 0.f ? s0 : 0.01f*s0;
        float w1 = s1 > 0.f ? s1 : 0.01f*s1;
        float v0 = (mk0 == 0.f) ? -1e6f : mk0*w0;
        float v1 = (mk1 == 0.f) ? -1e6f : mk1*w1;
        z[0][h] += __expf(v0);
        z[1][h] += __expf(v1);
      }
      r0 = n0; r1 = n1; r2 = n2; r3 = n3;
      j = jn; have = haven;
    }
  }
  #pragma unroll
  for (int r = 0; r < 2; r++)
    #pragma unroll
    for (int h = 0; h < 3; h++){
      float v = z[r][h];
      #pragma unroll
      for (int m = 32; m >= 1; m >>= 1) v += __shfl_xor(v, m, 64);
      if (lane == 0) red[w][r*3 + h] = v;
    }
  __syncthreads();
  float iZ[2][3];
  #pragma unroll
  for (int r = 0; r < 2; r++)
    #pragma unroll
    for (int h = 0; h < 3; h++)
      iZ[r][h] = 1.f/(red[0][r*3+h] + red[1][r*3+h] + red[2][r*3+h] + red[3][r*3+h]);

  // Pass B: combined normalized weight overwrites mask (own j only)
  for (int j = tid; j < 4000; j += 256){
    float mk0 = m0[j], mk1 = m1[j];
    float cv[3] = {c0[j], c1[j], c2[j]};
    float w0s = 0.f, w1s = 0.f;
    #pragma unroll
    for (int h = 0; h < 3; h++){
      float s0 = ai[0][h] + cv[h] + bh[h];
      float s1 = ai[1][h] + cv[h] + bh[h];
      float w0 = s0 > 0.f ? s0 : 0.01f*s0;
      float w1 = s1 > 0.f ? s1 : 0.01f*s1;
      float v0 = (mk0 == 0.f) ? -1e6f : mk0*w0;
      float v1 = (mk1 == 0.f) ? -1e6f : mk1*w1;
      w0s += __expf(v0) * iZ[0][h];
      w1s += __expf(v1) * iZ[1][h];
    }
    m0[j] = w0s * (1.f/3.f);
    m1[j] = w1s * (1.f/3.f);
  }
  __syncthreads();

  // Pass C: agg[r][d] = sum_j w[r][j]*h[j][d]; wave w owns j in [w*1000, (w+1)*1000)
  float acc0 = 0.f, acc1 = 0.f;
  const int jb = w * 1000;
  for (int jj = 0; jj < 1000; jj += 4){
    float4 w0 = *(const float4*)&m0[jb + jj];
    float4 w1 = *(const float4*)&m1[jb + jj];
    float w0a[4] = {w0.x, w0.y, w0.z, w0.w};
    float w1a[4] = {w1.x, w1.y, w1.z, w1.w};
    #pragma unroll
    for (int k = 0; k < 4; k++){
      float hv = hfin[(size_t)(jb + jj + k)*64 + lane];
      acc0 = fmaf(w0a[k], hv, acc0);
      acc1 = fmaf(w1a[k], hv, acc1);
    }
  }
  __syncthreads();                       // everyone done reading m0/m1
  m0[(w*2 + 0)*64 + lane] = acc0;        // reuse m0 as the cross-wave reduce buffer
  m0[(w*2 + 1)*64 + lane] = acc1;
  __syncthreads();
  if (tid < 128){
    int r = tid >> 6, d = tid & 63;
    float agg = m0[(0*2+r)*64 + d] + m0[(1*2+r)*64 + d]
              + m0[(2*2+r)*64 + d] + m0[(3*2+r)*64 + d];
    float term = hfin[(size_t)(i0+r)*64 + d]*fcw[d] + agg*fcw[64 + d];
    #pragma unroll
    for (int m = 32; m >= 1; m >>= 1) term += __shfl_xor(term, m, 64);
    if (d == 0) pred[i0 + r] = term + fcb[0];
  }
}

extern "C" void kernel_launch(void* const* d_in, const int* in_sizes, int n_in,
                              void* d_out, int out_size, void* d_ws, size_t ws_size,
                              hipStream_t stream) {
  const float* x    = (const float*)d_in[0];
  const float* rel  = (const float*)d_in[1];
  const float* Wih0 = (const float*)d_in[2];
  const float* Whh0 = (const float*)d_in[3];
  const float* bih0 = (const float*)d_in[4];
  const float* bhh0 = (const float*)d_in[5];
  const float* Wih1 = (const float*)d_in[6];
  const float* Whh1 = (const float*)d_in[7];
  const float* bih1 = (const float*)d_in[8];
  const float* bhh1 = (const float*)d_in[9];
  const float* W0   = (const float*)d_in[10];
  const float* b0   = (const float*)d_in[11];
  const float* W1   = (const float*)d_in[12];
  const float* b1   = (const float*)d_in[13];
  const float* W2   = (const float*)d_in[14];
  const float* b2   = (const float*)d_in[15];
  const float* fcw  = (const float*)d_in[16];
  const float* fcb  = (const float*)d_in[17];
  float* pred = (float*)d_out;
  float* hfin = (float*)d_ws;          // 4000*64 f32
  float* ac   = hfin + 4000*64;        // 6*4000 f32

  gru_kernel<<<dim3(250), dim3(256), 0, stream>>>(x, Wih0, Whh0, bih0, bhh0,
                                                  Wih1, Whh1, bih1, bhh1, hfin);
  ac_kernel<<<dim3(1000), dim3(256), 0, stream>>>(hfin, W0, W1, W2, ac);
  attn2_kernel<<<dim3(2000), dim3(256), 0, stream>>>(rel, hfin, ac, b0, b1, b2,
                                                     fcw, fcb, pred);
}

// Round 2
// 862.078 us; speedup vs baseline: 1.0172x; 1.0172x over previous
//
#include <hip/hip_runtime.h>

typedef __attribute__((ext_vector_type(8))) short bf16x8;
typedef __attribute__((ext_vector_type(4))) float f32x4;
typedef __attribute__((ext_vector_type(4))) float f4v;

__device__ __forceinline__ unsigned short f2bf(float f){
  unsigned u = __builtin_bit_cast(unsigned, f);
  u += 0x7FFFu + ((u >> 16) & 1u);
  return (unsigned short)(u >> 16);
}
__device__ __forceinline__ float bf2f(unsigned short b){
  unsigned u = ((unsigned)b) << 16;
  return __builtin_bit_cast(float, u);
}
__device__ __forceinline__ float sigmoidf_(float x){ return 1.f/(1.f + __expf(-x)); }
__device__ __forceinline__ float tanhf_(float x){
  float a = fabsf(x);
  float t = __expf(-2.f*a);
  float r = (1.f - t)/(1.f + t);
  return copysignf(r, x);
}

struct WF { bf16x8 hi, lo; };

// split-precision accumulate: hi-chain gets ah*Bhi, lo-chain gets al*Bhi + ah*Blo
__device__ __forceinline__ void mmsplit(bf16x8 ah, bf16x8 al, const WF& B,
                                        f32x4& Dh, f32x4& Dl){
  Dh = __builtin_amdgcn_mfma_f32_16x16x32_bf16(ah, B.hi, Dh, 0, 0, 0);
  Dl = __builtin_amdgcn_mfma_f32_16x16x32_bf16(al, B.hi, Dl, 0, 0, 0);
  Dl = __builtin_amdgcn_mfma_f32_16x16x32_bf16(ah, B.lo, Dl, 0, 0, 0);
}

__device__ __forceinline__ WF load_wf(const float* W, int ldk, int row, int k0, int kmax){
  WF f;
  #pragma unroll
  for (int j = 0; j < 8; j++){
    int k = k0 + j;
    float v = (k < kmax) ? W[row*ldk + k] : 0.f;
    unsigned short hb = f2bf(v);
    f.hi[j] = (short)hb;
    f.lo[j] = (short)f2bf(v - bf2f(hb));
  }
  return f;
}

// ---- GRU: 2 layers, split-wave skewed pipeline ----
// waves 0-3 (group A) compute layer 0 at step t; waves 4-7 (group B) compute
// layer 1 at step t-1 concurrently. One barrier per iteration. Per-step serial
// latency = max(L0, L1) instead of L0+L1, and 2 waves/SIMD hide each other.
__global__ __launch_bounds__(512, 2)
void gru_kernel(const float* __restrict__ x,
                const float* __restrict__ Wih0, const float* __restrict__ Whh0,
                const float* __restrict__ bih0, const float* __restrict__ bhh0,
                const float* __restrict__ Wih1, const float* __restrict__ Whh1,
                const float* __restrict__ bih1, const float* __restrict__ bhh1,
                float* __restrict__ hfin){
  __shared__ unsigned short xp_hi[16][60][8];
  __shared__ unsigned short xp_lo[16][60][8];
  __shared__ unsigned short h0hi[2][16][72], h0lo[2][16][72];
  __shared__ unsigned short h1hi[2][16][72], h1lo[2][16][72];

  const int tid  = threadIdx.x;
  const int lane = tid & 63;
  const int wv   = tid >> 6;          // 0..7
  const bool isA = (wv < 4);          // wave-uniform
  const int w    = wv & 3;
  const int c    = lane & 15;
  const int q    = lane >> 4;
  const int d    = w*16 + c;
  const int nbase = blockIdx.x * 16;

  for (int v = tid; v < 16*360; v += 512){
    int n = v / 360, rem = v % 360;
    int dd = rem / 60, tt = rem % 60;
    float f = x[(size_t)(nbase + n)*360 + rem];
    unsigned short hb = f2bf(f);
    xp_hi[n][tt][dd] = hb;
    xp_lo[n][tt][dd] = f2bf(f - bf2f(hb));
  }
  for (int v = tid; v < 16*60*2; v += 512){
    int n = v / 120, rem = v % 120;
    int tt = rem >> 1, dd = 6 + (rem & 1);
    xp_hi[n][tt][dd] = 0; xp_lo[n][tt][dd] = 0;
  }
  for (int v = tid; v < 2*16*72; v += 512){
    ((unsigned short*)h0hi)[v] = 0; ((unsigned short*)h0lo)[v] = 0;
    ((unsigned short*)h1hi)[v] = 0; ((unsigned short*)h1lo)[v] = 0;
  }

  // per-group biases (A: layer 0, B: layer 1)
  const float* bib = isA ? bih0 : bih1;
  const float* bhb = isA ? bhh0 : bhh1;
  const float bir = bib[d], biz = bib[64+d], bin = bib[128+d];
  const float bhr = bhb[d], bhz = bhb[64+d], bhn = bhb[128+d];

  // per-group weights: Bu = input-to-hidden, Bv = hidden-to-hidden
  WF Bu[3][2], Bv[3][2];
  #pragma unroll
  for (int g = 0; g < 3; g++){
    int row = g*64 + d;
    if (isA){
      Bu[g][0] = load_wf(Wih0, 6, row, q*8, 6);
      Bu[g][1] = Bu[g][0];                     // unused by A
      #pragma unroll
      for (int kt = 0; kt < 2; kt++)
        Bv[g][kt] = load_wf(Whh0, 64, row, kt*32 + q*8, 64);
    } else {
      #pragma unroll
      for (int kt = 0; kt < 2; kt++){
        Bu[g][kt] = load_wf(Wih1, 64, row, kt*32 + q*8, 64);
        Bv[g][kt] = load_wf(Whh1, 64, row, kt*32 + q*8, 64);
      }
    }
  }

  float hold[4] = {0,0,0,0};

  // layer-1 step body (group B), step index s
  auto stepB = [&](int s){
    const int rb = (s + 1) & 1;   // y1(s) buffer AND h1 write buffer
    const int sb = s & 1;         // h1 state buffer
    bf16x8 ayh[2], ayl[2], ahh[2], ahl[2];
    #pragma unroll
    for (int kt = 0; kt < 2; kt++){
      ayh[kt] = *(const bf16x8*)&h0hi[rb][c][kt*32 + q*8];
      ayl[kt] = *(const bf16x8*)&h0lo[rb][c][kt*32 + q*8];
      ahh[kt] = *(const bf16x8*)&h1hi[sb][c][kt*32 + q*8];
      ahl[kt] = *(const bf16x8*)&h1lo[sb][c][kt*32 + q*8];
    }
    f32x4 RH = {0,0,0,0}, RL = {0,0,0,0};
    f32x4 ZH = {0,0,0,0}, ZL = {0,0,0,0};
    f32x4 NIH = {0,0,0,0}, NIL = {0,0,0,0};
    f32x4 NHH = {0,0,0,0}, NHL = {0,0,0,0};
    #pragma unroll
    for (int kt = 0; kt < 2; kt++){
      mmsplit(ayh[kt], ayl[kt], Bu[0][kt], RH, RL);
      mmsplit(ayh[kt], ayl[kt], Bu[1][kt], ZH, ZL);
      mmsplit(ayh[kt], ayl[kt], Bu[2][kt], NIH, NIL);
      mmsplit(ahh[kt], ahl[kt], Bv[0][kt], RH, RL);
      mmsplit(ahh[kt], ahl[kt], Bv[1][kt], ZH, ZL);
      mmsplit(ahh[kt], ahl[kt], Bv[2][kt], NHH, NHL);
    }
    #pragma unroll
    for (int rI = 0; rI < 4; rI++){
      float rv = sigmoidf_(RH[rI] + RL[rI] + bir + bhr);
      float zv = sigmoidf_(ZH[rI] + ZL[rI] + biz + bhz);
      float nv = tanhf_(NIH[rI] + NIL[rI] + bin + rv*(NHH[rI] + NHL[rI] + bhn));
      float hnew = (1.f - zv)*nv + zv*hold[rI];
      hold[rI] = hnew;
      unsigned short hb = f2bf(hnew);
      int node = q*4 + rI;
      h1hi[rb][node][d] = hb;
      h1lo[rb][node][d] = f2bf(hnew - bf2f(hb));
    }
  };

  __syncthreads();

  #pragma unroll 1
  for (int t = 0; t < 60; t++){
    if (isA){
      // ---- layer 0, step t: reads h0[t&1] (state), writes h0[(t+1)&1] ----
      const int p  = t & 1;
      const int nb = p ^ 1;
      bf16x8 ah[2], al[2];
      #pragma unroll
      for (int kt = 0; kt < 2; kt++){
        ah[kt] = *(const bf16x8*)&h0hi[p][c][kt*32 + q*8];
        al[kt] = *(const bf16x8*)&h0lo[p][c][kt*32 + q*8];
      }
      bf16x8 axh = {}, axl = {};
      if (q == 0){
        axh = *(const bf16x8*)&xp_hi[c][t][0];
        axl = *(const bf16x8*)&xp_lo[c][t][0];
      }
      f32x4 RH = {0,0,0,0}, RL = {0,0,0,0};
      f32x4 ZH = {0,0,0,0}, ZL = {0,0,0,0};
      f32x4 NIH = {0,0,0,0}, NIL = {0,0,0,0};
      f32x4 NHH = {0,0,0,0}, NHL = {0,0,0,0};
      mmsplit(axh, axl, Bu[0][0], RH, RL);
      mmsplit(axh, axl, Bu[1][0], ZH, ZL);
      mmsplit(axh, axl, Bu[2][0], NIH, NIL);
      #pragma unroll
      for (int kt = 0; kt < 2; kt++){
        mmsplit(ah[kt], al[kt], Bv[0][kt], RH, RL);
        mmsplit(ah[kt], al[kt], Bv[1][kt], ZH, ZL);
        mmsplit(ah[kt], al[kt], Bv[2][kt], NHH, NHL);
      }
      #pragma unroll
      for (int rI = 0; rI < 4; rI++){
        float rv = sigmoidf_(RH[rI] + RL[rI] + bir + bhr);
        float zv = sigmoidf_(ZH[rI] + ZL[rI] + biz + bhz);
        float nv = tanhf_(NIH[rI] + NIL[rI] + bin + rv*(NHH[rI] + NHL[rI] + bhn));
        float hnew = (1.f - zv)*nv + zv*hold[rI];
        hold[rI] = hnew;
        unsigned short hb = f2bf(hnew);
        int node = q*4 + rI;
        h0hi[nb][node][d] = hb;
        h0lo[nb][node][d] = f2bf(hnew - bf2f(hb));
      }
    } else if (t > 0){
      stepB(t - 1);   // layer 1, step t-1 (y1(t-1) is in h0[t&1])
    }
    __syncthreads();
  }

  if (!isA){
    stepB(59);        // final layer-1 step (after loop's last barrier)
    #pragma unroll
    for (int rI = 0; rI < 4; rI++){
      int node = nbase + q*4 + rI;
      hfin[(size_t)node*64 + d] = hold[rI];
    }
  }
}

// ---------------- a,c per head: a=h@W[:64], c=h@W[64:] ----------------
__global__ void ac_kernel(const float* __restrict__ hfin,
                          const float* __restrict__ W0h, const float* __restrict__ W1h,
                          const float* __restrict__ W2h, float* __restrict__ ac){
  int lane = threadIdx.x & 63;
  int node = blockIdx.x*4 + (threadIdx.x >> 6);
  float hv = hfin[(size_t)node*64 + lane];
  const float* Ws[3] = {W0h, W1h, W2h};
  #pragma unroll
  for (int h = 0; h < 3; h++){
    float pa = hv * Ws[h][lane];
    float pc = hv * Ws[h][64 + lane];
    #pragma unroll
    for (int m = 32; m >= 1; m >>= 1){
      pa += __shfl_xor(pa, m, 64);
      pc += __shfl_xor(pc, m, 64);
    }
    if (lane == 0){
      ac[(size_t)(2*h)*4000 + node]   = pa;
      ac[(size_t)(2*h+1)*4000 + node] = pc;
    }
  }
}

// -------- fused 3-head masked softmax (no max pass) + aggregation + fc --------
__global__ __launch_bounds__(256, 3)
void attn2_kernel(const float* __restrict__ rel, const float* __restrict__ hfin,
                  const float* __restrict__ ac,
                  const float* __restrict__ b0p, const float* __restrict__ b1p,
                  const float* __restrict__ b2p,
                  const float* __restrict__ fcw, const float* __restrict__ fcb,
                  float* __restrict__ pred){
  __shared__ float m0[4000], m1[4000];     // mask, then combined weight
  __shared__ float red[4][8];

  const int tid  = threadIdx.x;
  const int lane = tid & 63;
  const int w    = tid >> 6;
  const int i0   = blockIdx.x * 2;
  const float bh[3] = {b0p[0], b1p[0], b2p[0]};

  const float* c0 = ac + 1*4000;
  const float* c1 = ac + 3*4000;
  const float* c2 = ac + 5*4000;

  float ai[2][3];
  #pragma unroll
  for (int r = 0; r < 2; r++)
    #pragma unroll
    for (int h = 0; h < 3; h++)
      ai[r][h] = ac[(size_t)(2*h)*4000 + i0 + r];

  float z[2][3] = {{0.f,0.f,0.f},{0.f,0.f,0.f}};

  // Pass A: stream rel once with register prefetch; masks -> LDS; Z accum (no max)
  {
    int j = tid;
    bool have = (j < 4000);
    f4v r0, r1, r2, r3;
    if (have){
      const f4v* rp0 = (const f4v*)(rel + ((size_t)i0*4000 + j)*8);
      const f4v* rp1 = (const f4v*)(rel + ((size_t)(i0+1)*4000 + j)*8);
      r0 = __builtin_nontemporal_load(rp0);
      r1 = __builtin_nontemporal_load(rp0 + 1);
      r2 = __builtin_nontemporal_load(rp1);
      r3 = __builtin_nontemporal_load(rp1 + 1);
    }
    while (have){
      int jn = j + 256;
      bool haven = (jn < 4000);
      f4v n0, n1, n2, n3;
      if (haven){
        const f4v* rp0 = (const f4v*)(rel + ((size_t)i0*4000 + jn)*8);
        const f4v* rp1 = (const f4v*)(rel + ((size_t)(i0+1)*4000 + jn)*8);
        n0 = __builtin_nontemporal_load(rp0);
        n1 = __builtin_nontemporal_load(rp0 + 1);
        n2 = __builtin_nontemporal_load(rp1);
        n3 = __builtin_nontemporal_load(rp1 + 1);
      }
      float mk0 = r0[0]+r0[1]+r0[2]+r0[3] + r1[0]+r1[1]+r1[2]+r1[3];
      float mk1 = r2[0]+r2[1]+r2[2]+r2[3] + r3[0]+r3[1]+r3[2]+r3[3];
      m0[j] = mk0; m1[j] = mk1;
      float cv[3] = {c0[j], c1[j], c2[j]};
      #pragma unroll
      for (int h = 0; h < 3; h++){
        float s0 = ai[0][h] + cv[h] + bh[h];
        float s1 = ai[1][h] + cv[h] + bh[h];
        float w0 = s0 > 0.f ? s0 : 0.01f*s0;
        float w1 = s1 > 0.f ? s1 : 0.01f*s1;
        float v0 = (mk0 == 0.f) ? -1e6f : mk0*w0;
        float v1 = (mk1 == 0.f) ? -1e6f : mk1*w1;
        z[0][h] += __expf(v0);
        z[1][h] += __expf(v1);
      }
      r0 = n0; r1 = n1; r2 = n2; r3 = n3;
      j = jn; have = haven;
    }
  }
  #pragma unroll
  for (int r = 0; r < 2; r++)
    #pragma unroll
    for (int h = 0; h < 3; h++){
      float v = z[r][h];
      #pragma unroll
      for (int m = 32; m >= 1; m >>= 1) v += __shfl_xor(v, m, 64);
      if (lane == 0) red[w][r*3 + h] = v;
    }
  __syncthreads();
  float iZ[2][3];
  #pragma unroll
  for (int r = 0; r < 2; r++)
    #pragma unroll
    for (int h = 0; h < 3; h++)
      iZ[r][h] = 1.f/(red[0][r*3+h] + red[1][r*3+h] + red[2][r*3+h] + red[3][r*3+h]);

  // Pass B: combined normalized weight overwrites mask (own j only)
  for (int j = tid; j < 4000; j += 256){
    float mk0 = m0[j], mk1 = m1[j];
    float cv[3] = {c0[j], c1[j], c2[j]};
    float w0s = 0.f, w1s = 0.f;
    #pragma unroll
    for (int h = 0; h < 3; h++){
      float s0 = ai[0][h] + cv[h] + bh[h];
      float s1 = ai[1][h] + cv[h] + bh[h];
      float w0 = s0 > 0.f ? s0 : 0.01f*s0;
      float w1 = s1 > 0.f ? s1 : 0.01f*s1;
      float v0 = (mk0 == 0.f) ? -1e6f : mk0*w0;
      float v1 = (mk1 == 0.f) ? -1e6f : mk1*w1;
      w0s += __expf(v0) * iZ[0][h];
      w1s += __expf(v1) * iZ[1][h];
    }
    m0[j] = w0s * (1.f/3.f);
    m1[j] = w1s * (1.f/3.f);
  }
  __syncthreads();

  // Pass C: agg[r][d] = sum_j w[r][j]*h[j][d]; wave w owns j in [w*1000, (w+1)*1000)
  float acc0 = 0.f, acc1 = 0.f;
  const int jb = w * 1000;
  for (int jj = 0; jj < 1000; jj += 4){
    float4 w0 = *(const float4*)&m0[jb + jj];
    float4 w1 = *(const float4*)&m1[jb + jj];
    float w0a[4] = {w0.x, w0.y, w0.z, w0.w};
    float w1a[4] = {w1.x, w1.y, w1.z, w1.w};
    #pragma unroll
    for (int k = 0; k < 4; k++){
      float hv = hfin[(size_t)(jb + jj + k)*64 + lane];
      acc0 = fmaf(w0a[k], hv, acc0);
      acc1 = fmaf(w1a[k], hv, acc1);
    }
  }
  __syncthreads();                       // everyone done reading m0/m1
  m0[(w*2 + 0)*64 + lane] = acc0;        // reuse m0 as the cross-wave reduce buffer
  m0[(w*2 + 1)*64 + lane] = acc1;
  __syncthreads();
  if (tid < 128){
    int r = tid >> 6, d = tid & 63;
    float agg = m0[(0*2+r)*64 + d] + m0[(1*2+r)*64 + d]
              + m0[(2*2+r)*64 + d] + m0[(3*2+r)*64 + d];
    float term = hfin[(size_t)(i0+r)*64 + d]*fcw[d] + agg*fcw[64 + d];
    #pragma unroll
    for (int m = 32; m >= 1; m >>= 1) term += __shfl_xor(term, m, 64);
    if (d == 0) pred[i0 + r] = term + fcb[0];
  }
}

extern "C" void kernel_launch(void* const* d_in, const int* in_sizes, int n_in,
                              void* d_out, int out_size, void* d_ws, size_t ws_size,
                              hipStream_t stream) {
  const float* x    = (const float*)d_in[0];
  const float* rel  = (const float*)d_in[1];
  const float* Wih0 = (const float*)d_in[2];
  const float* Whh0 = (const float*)d_in[3];
  const float* bih0 = (const float*)d_in[4];
  const float* bhh0 = (const float*)d_in[5];
  const float* Wih1 = (const float*)d_in[6];
  const float* Whh1 = (const float*)d_in[7];
  const float* bih1 = (const float*)d_in[8];
  const float* bhh1 = (const float*)d_in[9];
  const float* W0   = (const float*)d_in[10];
  const float* b0   = (const float*)d_in[11];
  const float* W1   = (const float*)d_in[12];
  const float* b1   = (const float*)d_in[13];
  const float* W2   = (const float*)d_in[14];
  const float* b2   = (const float*)d_in[15];
  const float* fcw  = (const float*)d_in[16];
  const float* fcb  = (const float*)d_in[17];
  float* pred = (float*)d_out;
  float* hfin = (float*)d_ws;          // 4000*64 f32
  float* ac   = hfin + 4000*64;        // 6*4000 f32

  gru_kernel<<<dim3(250), dim3(512), 0, stream>>>(x, Wih0, Whh0, bih0, bhh0,
                                                  Wih1, Whh1, bih1, bhh1, hfin);
  ac_kernel<<<dim3(1000), dim3(256), 0, stream>>>(hfin, W0, W1, W2, ac);
  attn2_kernel<<<dim3(2000), dim3(256), 0, stream>>>(rel, hfin, ac, b0, b1, b2,
                                                     fcw, fcb, pred);
}

// Round 3
// 860.220 us; speedup vs baseline: 1.0194x; 1.0022x over previous
//
#include <hip/hip_runtime.h>

typedef __attribute__((ext_vector_type(8))) short bf16x8;
typedef __attribute__((ext_vector_type(4))) float f32x4;
typedef __attribute__((ext_vector_type(4))) float f4v;

__device__ __forceinline__ unsigned short f2bf(float f){
  unsigned u = __builtin_bit_cast(unsigned, f);
  u += 0x7FFFu + ((u >> 16) & 1u);
  return (unsigned short)(u >> 16);
}
__device__ __forceinline__ float bf2f(unsigned short b){
  unsigned u = ((unsigned)b) << 16;
  return __builtin_bit_cast(float, u);
}
__device__ __forceinline__ float sigmoidf_(float x){ return 1.f/(1.f + __expf(-x)); }
__device__ __forceinline__ float tanhf_(float x){
  float a = fabsf(x);
  float t = __expf(-2.f*a);
  float r = (1.f - t)/(1.f + t);
  return copysignf(r, x);
}

struct WF { bf16x8 hi, lo; };

// split-precision accumulate: hi-chain gets ah*Bhi, lo-chain gets al*Bhi + ah*Blo
__device__ __forceinline__ void mmsplit(bf16x8 ah, bf16x8 al, const WF& B,
                                        f32x4& Dh, f32x4& Dl){
  Dh = __builtin_amdgcn_mfma_f32_16x16x32_bf16(ah, B.hi, Dh, 0, 0, 0);
  Dl = __builtin_amdgcn_mfma_f32_16x16x32_bf16(al, B.hi, Dl, 0, 0, 0);
  Dl = __builtin_amdgcn_mfma_f32_16x16x32_bf16(ah, B.lo, Dl, 0, 0, 0);
}

__device__ __forceinline__ WF load_wf(const float* W, int ldk, int row, int k0, int kmax){
  WF f;
  #pragma unroll
  for (int j = 0; j < 8; j++){
    int k = k0 + j;
    float v = (k < kmax) ? W[row*ldk + k] : 0.f;
    unsigned short hb = f2bf(v);
    f.hi[j] = (short)hb;
    f.lo[j] = (short)f2bf(v - bf2f(hb));
  }
  return f;
}

// ---- GRU: 2 layers, split-wave skewed pipeline ----
__global__ __launch_bounds__(512, 2)
void gru_kernel(const float* __restrict__ x,
                const float* __restrict__ Wih0, const float* __restrict__ Whh0,
                const float* __restrict__ bih0, const float* __restrict__ bhh0,
                const float* __restrict__ Wih1, const float* __restrict__ Whh1,
                const float* __restrict__ bih1, const float* __restrict__ bhh1,
                float* __restrict__ hfin){
  __shared__ unsigned short xp_hi[16][60][8];
  __shared__ unsigned short xp_lo[16][60][8];
  __shared__ unsigned short h0hi[2][16][72], h0lo[2][16][72];
  __shared__ unsigned short h1hi[2][16][72], h1lo[2][16][72];

  const int tid  = threadIdx.x;
  const int lane = tid & 63;
  const int wv   = tid >> 6;          // 0..7
  const bool isA = (wv < 4);          // wave-uniform
  const int w    = wv & 3;
  const int c    = lane & 15;
  const int q    = lane >> 4;
  const int d    = w*16 + c;
  const int nbase = blockIdx.x * 16;

  for (int v = tid; v < 16*360; v += 512){
    int n = v / 360, rem = v % 360;
    int dd = rem / 60, tt = rem % 60;
    float f = x[(size_t)(nbase + n)*360 + rem];
    unsigned short hb = f2bf(f);
    xp_hi[n][tt][dd] = hb;
    xp_lo[n][tt][dd] = f2bf(f - bf2f(hb));
  }
  for (int v = tid; v < 16*60*2; v += 512){
    int n = v / 120, rem = v % 120;
    int tt = rem >> 1, dd = 6 + (rem & 1);
    xp_hi[n][tt][dd] = 0; xp_lo[n][tt][dd] = 0;
  }
  for (int v = tid; v < 2*16*72; v += 512){
    ((unsigned short*)h0hi)[v] = 0; ((unsigned short*)h0lo)[v] = 0;
    ((unsigned short*)h1hi)[v] = 0; ((unsigned short*)h1lo)[v] = 0;
  }

  const float* bib = isA ? bih0 : bih1;
  const float* bhb = isA ? bhh0 : bhh1;
  const float bir = bib[d], biz = bib[64+d], bin = bib[128+d];
  const float bhr = bhb[d], bhz = bhb[64+d], bhn = bhb[128+d];

  WF Bu[3][2], Bv[3][2];
  #pragma unroll
  for (int g = 0; g < 3; g++){
    int row = g*64 + d;
    if (isA){
      Bu[g][0] = load_wf(Wih0, 6, row, q*8, 6);
      Bu[g][1] = Bu[g][0];
      #pragma unroll
      for (int kt = 0; kt < 2; kt++)
        Bv[g][kt] = load_wf(Whh0, 64, row, kt*32 + q*8, 64);
    } else {
      #pragma unroll
      for (int kt = 0; kt < 2; kt++){
        Bu[g][kt] = load_wf(Wih1, 64, row, kt*32 + q*8, 64);
        Bv[g][kt] = load_wf(Whh1, 64, row, kt*32 + q*8, 64);
      }
    }
  }

  float hold[4] = {0,0,0,0};

  auto stepB = [&](int s){
    const int rb = (s + 1) & 1;
    const int sb = s & 1;
    bf16x8 ayh[2], ayl[2], ahh[2], ahl[2];
    #pragma unroll
    for (int kt = 0; kt < 2; kt++){
      ayh[kt] = *(const bf16x8*)&h0hi[rb][c][kt*32 + q*8];
      ayl[kt] = *(const bf16x8*)&h0lo[rb][c][kt*32 + q*8];
      ahh[kt] = *(const bf16x8*)&h1hi[sb][c][kt*32 + q*8];
      ahl[kt] = *(const bf16x8*)&h1lo[sb][c][kt*32 + q*8];
    }
    f32x4 RH = {0,0,0,0}, RL = {0,0,0,0};
    f32x4 ZH = {0,0,0,0}, ZL = {0,0,0,0};
    f32x4 NIH = {0,0,0,0}, NIL = {0,0,0,0};
    f32x4 NHH = {0,0,0,0}, NHL = {0,0,0,0};
    #pragma unroll
    for (int kt = 0; kt < 2; kt++){
      mmsplit(ayh[kt], ayl[kt], Bu[0][kt], RH, RL);
      mmsplit(ayh[kt], ayl[kt], Bu[1][kt], ZH, ZL);
      mmsplit(ayh[kt], ayl[kt], Bu[2][kt], NIH, NIL);
      mmsplit(ahh[kt], ahl[kt], Bv[0][kt], RH, RL);
      mmsplit(ahh[kt], ahl[kt], Bv[1][kt], ZH, ZL);
      mmsplit(ahh[kt], ahl[kt], Bv[2][kt], NHH, NHL);
    }
    #pragma unroll
    for (int rI = 0; rI < 4; rI++){
      float rv = sigmoidf_(RH[rI] + RL[rI] + bir + bhr);
      float zv = sigmoidf_(ZH[rI] + ZL[rI] + biz + bhz);
      float nv = tanhf_(NIH[rI] + NIL[rI] + bin + rv*(NHH[rI] + NHL[rI] + bhn));
      float hnew = (1.f - zv)*nv + zv*hold[rI];
      hold[rI] = hnew;
      unsigned short hb = f2bf(hnew);
      int node = q*4 + rI;
      h1hi[rb][node][d] = hb;
      h1lo[rb][node][d] = f2bf(hnew - bf2f(hb));
    }
  };

  __syncthreads();

  #pragma unroll 1
  for (int t = 0; t < 60; t++){
    if (isA){
      const int p  = t & 1;
      const int nb = p ^ 1;
      bf16x8 ah[2], al[2];
      #pragma unroll
      for (int kt = 0; kt < 2; kt++){
        ah[kt] = *(const bf16x8*)&h0hi[p][c][kt*32 + q*8];
        al[kt] = *(const bf16x8*)&h0lo[p][c][kt*32 + q*8];
      }
      bf16x8 axh = {}, axl = {};
      if (q == 0){
        axh = *(const bf16x8*)&xp_hi[c][t][0];
        axl = *(const bf16x8*)&xp_lo[c][t][0];
      }
      f32x4 RH = {0,0,0,0}, RL = {0,0,0,0};
      f32x4 ZH = {0,0,0,0}, ZL = {0,0,0,0};
      f32x4 NIH = {0,0,0,0}, NIL = {0,0,0,0};
      f32x4 NHH = {0,0,0,0}, NHL = {0,0,0,0};
      mmsplit(axh, axl, Bu[0][0], RH, RL);
      mmsplit(axh, axl, Bu[1][0], ZH, ZL);
      mmsplit(axh, axl, Bu[2][0], NIH, NIL);
      #pragma unroll
      for (int kt = 0; kt < 2; kt++){
        mmsplit(ah[kt], al[kt], Bv[0][kt], RH, RL);
        mmsplit(ah[kt], al[kt], Bv[1][kt], ZH, ZL);
        mmsplit(ah[kt], al[kt], Bv[2][kt], NHH, NHL);
      }
      #pragma unroll
      for (int rI = 0; rI < 4; rI++){
        float rv = sigmoidf_(RH[rI] + RL[rI] + bir + bhr);
        float zv = sigmoidf_(ZH[rI] + ZL[rI] + biz + bhz);
        float nv = tanhf_(NIH[rI] + NIL[rI] + bin + rv*(NHH[rI] + NHL[rI] + bhn));
        float hnew = (1.f - zv)*nv + zv*hold[rI];
        hold[rI] = hnew;
        unsigned short hb = f2bf(hnew);
        int node = q*4 + rI;
        h0hi[nb][node][d] = hb;
        h0lo[nb][node][d] = f2bf(hnew - bf2f(hb));
      }
    } else if (t > 0){
      stepB(t - 1);
    }
    __syncthreads();
  }

  if (!isA){
    stepB(59);
    #pragma unroll
    for (int rI = 0; rI < 4; rI++){
      int node = nbase + q*4 + rI;
      hfin[(size_t)node*64 + d] = hold[rI];
    }
  }
}

// ---------------- a,c per head: a=h@W[:64], c=h@W[64:] ----------------
__global__ void ac_kernel(const float* __restrict__ hfin,
                          const float* __restrict__ W0h, const float* __restrict__ W1h,
                          const float* __restrict__ W2h, float* __restrict__ ac){
  int lane = threadIdx.x & 63;
  int node = blockIdx.x*4 + (threadIdx.x >> 6);
  float hv = hfin[(size_t)node*64 + lane];
  const float* Ws[3] = {W0h, W1h, W2h};
  #pragma unroll
  for (int h = 0; h < 3; h++){
    float pa = hv * Ws[h][lane];
    float pc = hv * Ws[h][64 + lane];
    #pragma unroll
    for (int m = 32; m >= 1; m >>= 1){
      pa += __shfl_xor(pa, m, 64);
      pc += __shfl_xor(pc, m, 64);
    }
    if (lane == 0){
      ac[(size_t)(2*h)*4000 + node]   = pa;
      ac[(size_t)(2*h+1)*4000 + node] = pc;
    }
  }
}

// -------- fused 3-head masked softmax (no max pass) + aggregation + fc --------
// 2 rows per WG, 2000 WGs, depth-2 register-prefetched rel stream, 4 blocks/CU.
__global__ __launch_bounds__(256, 4)
void attn2_kernel(const float* __restrict__ rel, const float* __restrict__ hfin,
                  const float* __restrict__ ac,
                  const float* __restrict__ b0p, const float* __restrict__ b1p,
                  const float* __restrict__ b2p,
                  const float* __restrict__ fcw, const float* __restrict__ fcb,
                  float* __restrict__ pred){
  __shared__ float m0[4000], m1[4000];     // mask, then combined weight
  __shared__ float red[4][8];

  const int tid  = threadIdx.x;
  const int lane = tid & 63;
  const int w    = tid >> 6;
  const int i0   = blockIdx.x * 2;
  const float bh[3] = {b0p[0], b1p[0], b2p[0]};

  const float* c0 = ac + 1*4000;
  const float* c1 = ac + 3*4000;
  const float* c2 = ac + 5*4000;

  float ai[2][3];
  #pragma unroll
  for (int r = 0; r < 2; r++)
    #pragma unroll
    for (int h = 0; h < 3; h++)
      ai[r][h] = ac[(size_t)(2*h)*4000 + i0 + r];

  float z[2][3] = {{0.f,0.f,0.f},{0.f,0.f,0.f}};

  // Pass A: stream rel once with DEPTH-2 register prefetch; masks -> LDS; Z accum
  {
    const size_t base0 = (size_t)i0*4000;
    const size_t base1 = (size_t)(i0+1)*4000;
    int j = tid;
    bool h0 = (j < 4000);
    bool h1 = (j + 256 < 4000);
    f4v a0, a1, a2, a3, b0, b1, b2, b3;
    if (h0){
      const f4v* rp0 = (const f4v*)(rel + (base0 + j)*8);
      const f4v* rp1 = (const f4v*)(rel + (base1 + j)*8);
      a0 = __builtin_nontemporal_load(rp0);
      a1 = __builtin_nontemporal_load(rp0 + 1);
      a2 = __builtin_nontemporal_load(rp1);
      a3 = __builtin_nontemporal_load(rp1 + 1);
    }
    if (h1){
      const f4v* rp0 = (const f4v*)(rel + (base0 + j + 256)*8);
      const f4v* rp1 = (const f4v*)(rel + (base1 + j + 256)*8);
      b0 = __builtin_nontemporal_load(rp0);
      b1 = __builtin_nontemporal_load(rp0 + 1);
      b2 = __builtin_nontemporal_load(rp1);
      b3 = __builtin_nontemporal_load(rp1 + 1);
    }
    while (h0){
      int j2 = j + 512;
      bool h2 = (j2 < 4000);
      f4v c0v, c1v, c2v, c3v;
      if (h2){
        const f4v* rp0 = (const f4v*)(rel + (base0 + j2)*8);
        const f4v* rp1 = (const f4v*)(rel + (base1 + j2)*8);
        c0v = __builtin_nontemporal_load(rp0);
        c1v = __builtin_nontemporal_load(rp0 + 1);
        c2v = __builtin_nontemporal_load(rp1);
        c3v = __builtin_nontemporal_load(rp1 + 1);
      }
      float mk0 = a0[0]+a0[1]+a0[2]+a0[3] + a1[0]+a1[1]+a1[2]+a1[3];
      float mk1 = a2[0]+a2[1]+a2[2]+a2[3] + a3[0]+a3[1]+a3[2]+a3[3];
      m0[j] = mk0; m1[j] = mk1;
      float cv[3] = {c0[j], c1[j], c2[j]};
      #pragma unroll
      for (int h = 0; h < 3; h++){
        float s0 = ai[0][h] + cv[h] + bh[h];
        float s1 = ai[1][h] + cv[h] + bh[h];
        float w0 = s0 > 0.f ? s0 : 0.01f*s0;
        float w1 = s1 > 0.f ? s1 : 0.01f*s1;
        float v0 = (mk0 == 0.f) ? -1e6f : mk0*w0;
        float v1 = (mk1 == 0.f) ? -1e6f : mk1*w1;
        z[0][h] += __expf(v0);
        z[1][h] += __expf(v1);
      }
      a0 = b0; a1 = b1; a2 = b2; a3 = b3;
      b0 = c0v; b1 = c1v; b2 = c2v; b3 = c3v;
      j += 256; h0 = h1; h1 = h2;
    }
  }
  #pragma unroll
  for (int r = 0; r < 2; r++)
    #pragma unroll
    for (int h = 0; h < 3; h++){
      float v = z[r][h];
      #pragma unroll
      for (int m = 32; m >= 1; m >>= 1) v += __shfl_xor(v, m, 64);
      if (lane == 0) red[w][r*3 + h] = v;
    }
  __syncthreads();
  float iZ[2][3];
  #pragma unroll
  for (int r = 0; r < 2; r++)
    #pragma unroll
    for (int h = 0; h < 3; h++)
      iZ[r][h] = 1.f/(red[0][r*3+h] + red[1][r*3+h] + red[2][r*3+h] + red[3][r*3+h]);

  // Pass B: combined normalized weight overwrites mask (own j only)
  for (int j = tid; j < 4000; j += 256){
    float mk0 = m0[j], mk1 = m1[j];
    float cv[3] = {c0[j], c1[j], c2[j]};
    float w0s = 0.f, w1s = 0.f;
    #pragma unroll
    for (int h = 0; h < 3; h++){
      float s0 = ai[0][h] + cv[h] + bh[h];
      float s1 = ai[1][h] + cv[h] + bh[h];
      float w0 = s0 > 0.f ? s0 : 0.01f*s0;
      float w1 = s1 > 0.f ? s1 : 0.01f*s1;
      float v0 = (mk0 == 0.f) ? -1e6f : mk0*w0;
      float v1 = (mk1 == 0.f) ? -1e6f : mk1*w1;
      w0s += __expf(v0) * iZ[0][h];
      w1s += __expf(v1) * iZ[1][h];
    }
    m0[j] = w0s * (1.f/3.f);
    m1[j] = w1s * (1.f/3.f);
  }
  __syncthreads();

  // Pass C: agg[r][d] = sum_j w[r][j]*h[j][d]; wave w owns j in [w*1000, (w+1)*1000)
  float acc0 = 0.f, acc1 = 0.f;
  const int jb = w * 1000;
  for (int jj = 0; jj < 1000; jj += 4){
    float4 w0 = *(const float4*)&m0[jb + jj];
    float4 w1 = *(const float4*)&m1[jb + jj];
    float w0a[4] = {w0.x, w0.y, w0.z, w0.w};
    float w1a[4] = {w1.x, w1.y, w1.z, w1.w};
    #pragma unroll
    for (int k = 0; k < 4; k++){
      float hv = hfin[(size_t)(jb + jj + k)*64 + lane];
      acc0 = fmaf(w0a[k], hv, acc0);
      acc1 = fmaf(w1a[k], hv, acc1);
    }
  }
  __syncthreads();                       // everyone done reading m0/m1
  m0[(w*2 + 0)*64 + lane] = acc0;        // reuse m0 as the cross-wave reduce buffer
  m0[(w*2 + 1)*64 + lane] = acc1;
  __syncthreads();
  if (tid < 128){
    int r = tid >> 6, d = tid & 63;
    float agg = m0[(0*2+r)*64 + d] + m0[(1*2+r)*64 + d]
              + m0[(2*2+r)*64 + d] + m0[(3*2+r)*64 + d];
    float term = hfin[(size_t)(i0+r)*64 + d]*fcw[d] + agg*fcw[64 + d];
    #pragma unroll
    for (int m = 32; m >= 1; m >>= 1) term += __shfl_xor(term, m, 64);
    if (d == 0) pred[i0 + r] = term + fcb[0];
  }
}

extern "C" void kernel_launch(void* const* d_in, const int* in_sizes, int n_in,
                              void* d_out, int out_size, void* d_ws, size_t ws_size,
                              hipStream_t stream) {
  const float* x    = (const float*)d_in[0];
  const float* rel  = (const float*)d_in[1];
  const float* Wih0 = (const float*)d_in[2];
  const float* Whh0 = (const float*)d_in[3];
  const float* bih0 = (const float*)d_in[4];
  const float* bhh0 = (const float*)d_in[5];
  const float* Wih1 = (const float*)d_in[6];
  const float* Whh1 = (const float*)d_in[7];
  const float* bih1 = (const float*)d_in[8];
  const float* bhh1 = (const float*)d_in[9];
  const float* W0   = (const float*)d_in[10];
  const float* b0   = (const float*)d_in[11];
  const float* W1   = (const float*)d_in[12];
  const float* b1   = (const float*)d_in[13];
  const float* W2   = (const float*)d_in[14];
  const float* b2   = (const float*)d_in[15];
  const float* fcw  = (const float*)d_in[16];
  const float* fcb  = (const float*)d_in[17];
  float* pred = (float*)d_out;
  float* hfin = (float*)d_ws;          // 4000*64 f32
  float* ac   = hfin + 4000*64;        // 6*4000 f32

  gru_kernel<<<dim3(250), dim3(512), 0, stream>>>(x, Wih0, Whh0, bih0, bhh0,
                                                  Wih1, Whh1, bih1, bhh1, hfin);
  ac_kernel<<<dim3(1000), dim3(256), 0, stream>>>(hfin, W0, W1, W2, ac);
  attn2_kernel<<<dim3(2000), dim3(256), 0, stream>>>(rel, hfin, ac, b0, b1, b2,
                                                     fcw, fcb, pred);
}

// Round 4
// 778.362 us; speedup vs baseline: 1.1266x; 1.1052x over previous
//
#include <hip/hip_runtime.h>

typedef __attribute__((ext_vector_type(8))) short bf16x8;
typedef __attribute__((ext_vector_type(4))) float f32x4;
typedef __attribute__((ext_vector_type(4))) float f4v;

__device__ __forceinline__ unsigned short f2bf(float f){
  unsigned u = __builtin_bit_cast(unsigned, f);
  u += 0x7FFFu + ((u >> 16) & 1u);
  return (unsigned short)(u >> 16);
}
__device__ __forceinline__ float bf2f(unsigned short b){
  unsigned u = ((unsigned)b) << 16;
  return __builtin_bit_cast(float, u);
}
__device__ __forceinline__ float sigmoidf_(float x){ return 1.f/(1.f + __expf(-x)); }
__device__ __forceinline__ float tanhf_(float x){
  float a = fabsf(x);
  float t = __expf(-2.f*a);
  float r = (1.f - t)/(1.f + t);
  return copysignf(r, x);
}

struct WF { bf16x8 hi, lo; };

// split-precision accumulate: hi-chain gets ah*Bhi, lo-chain gets al*Bhi + ah*Blo
__device__ __forceinline__ void mmsplit(bf16x8 ah, bf16x8 al, const WF& B,
                                        f32x4& Dh, f32x4& Dl){
  Dh = __builtin_amdgcn_mfma_f32_16x16x32_bf16(ah, B.hi, Dh, 0, 0, 0);
  Dl = __builtin_amdgcn_mfma_f32_16x16x32_bf16(al, B.hi, Dl, 0, 0, 0);
  Dl = __builtin_amdgcn_mfma_f32_16x16x32_bf16(ah, B.lo, Dl, 0, 0, 0);
}

__device__ __forceinline__ WF load_wf(const float* W, int ldk, int row, int k0, int kmax){
  WF f;
  #pragma unroll
  for (int j = 0; j < 8; j++){
    int k = k0 + j;
    float v = (k < kmax) ? W[row*ldk + k] : 0.f;
    unsigned short hb = f2bf(v);
    f.hi[j] = (short)hb;
    f.lo[j] = (short)f2bf(v - bf2f(hb));
  }
  return f;
}

// ---- GRU: 2 layers, split-wave skewed pipeline (unchanged from R2 win) ----
__global__ __launch_bounds__(512, 2)
void gru_kernel(const float* __restrict__ x,
                const float* __restrict__ Wih0, const float* __restrict__ Whh0,
                const float* __restrict__ bih0, const float* __restrict__ bhh0,
                const float* __restrict__ Wih1, const float* __restrict__ Whh1,
                const float* __restrict__ bih1, const float* __restrict__ bhh1,
                float* __restrict__ hfin){
  __shared__ unsigned short xp_hi[16][60][8];
  __shared__ unsigned short xp_lo[16][60][8];
  __shared__ unsigned short h0hi[2][16][72], h0lo[2][16][72];
  __shared__ unsigned short h1hi[2][16][72], h1lo[2][16][72];

  const int tid  = threadIdx.x;
  const int lane = tid & 63;
  const int wv   = tid >> 6;          // 0..7
  const bool isA = (wv < 4);          // wave-uniform
  const int w    = wv & 3;
  const int c    = lane & 15;
  const int q    = lane >> 4;
  const int d    = w*16 + c;
  const int nbase = blockIdx.x * 16;

  for (int v = tid; v < 16*360; v += 512){
    int n = v / 360, rem = v % 360;
    int dd = rem / 60, tt = rem % 60;
    float f = x[(size_t)(nbase + n)*360 + rem];
    unsigned short hb = f2bf(f);
    xp_hi[n][tt][dd] = hb;
    xp_lo[n][tt][dd] = f2bf(f - bf2f(hb));
  }
  for (int v = tid; v < 16*60*2; v += 512){
    int n = v / 120, rem = v % 120;
    int tt = rem >> 1, dd = 6 + (rem & 1);
    xp_hi[n][tt][dd] = 0; xp_lo[n][tt][dd] = 0;
  }
  for (int v = tid; v < 2*16*72; v += 512){
    ((unsigned short*)h0hi)[v] = 0; ((unsigned short*)h0lo)[v] = 0;
    ((unsigned short*)h1hi)[v] = 0; ((unsigned short*)h1lo)[v] = 0;
  }

  const float* bib = isA ? bih0 : bih1;
  const float* bhb = isA ? bhh0 : bhh1;
  const float bir = bib[d], biz = bib[64+d], bin = bib[128+d];
  const float bhr = bhb[d], bhz = bhb[64+d], bhn = bhb[128+d];

  WF Bu[3][2], Bv[3][2];
  #pragma unroll
  for (int g = 0; g < 3; g++){
    int row = g*64 + d;
    if (isA){
      Bu[g][0] = load_wf(Wih0, 6, row, q*8, 6);
      Bu[g][1] = Bu[g][0];
      #pragma unroll
      for (int kt = 0; kt < 2; kt++)
        Bv[g][kt] = load_wf(Whh0, 64, row, kt*32 + q*8, 64);
    } else {
      #pragma unroll
      for (int kt = 0; kt < 2; kt++){
        Bu[g][kt] = load_wf(Wih1, 64, row, kt*32 + q*8, 64);
        Bv[g][kt] = load_wf(Whh1, 64, row, kt*32 + q*8, 64);
      }
    }
  }

  float hold[4] = {0,0,0,0};

  auto stepB = [&](int s){
    const int rb = (s + 1) & 1;
    const int sb = s & 1;
    bf16x8 ayh[2], ayl[2], ahh[2], ahl[2];
    #pragma unroll
    for (int kt = 0; kt < 2; kt++){
      ayh[kt] = *(const bf16x8*)&h0hi[rb][c][kt*32 + q*8];
      ayl[kt] = *(const bf16x8*)&h0lo[rb][c][kt*32 + q*8];
      ahh[kt] = *(const bf16x8*)&h1hi[sb][c][kt*32 + q*8];
      ahl[kt] = *(const bf16x8*)&h1lo[sb][c][kt*32 + q*8];
    }
    f32x4 RH = {0,0,0,0}, RL = {0,0,0,0};
    f32x4 ZH = {0,0,0,0}, ZL = {0,0,0,0};
    f32x4 NIH = {0,0,0,0}, NIL = {0,0,0,0};
    f32x4 NHH = {0,0,0,0}, NHL = {0,0,0,0};
    #pragma unroll
    for (int kt = 0; kt < 2; kt++){
      mmsplit(ayh[kt], ayl[kt], Bu[0][kt], RH, RL);
      mmsplit(ayh[kt], ayl[kt], Bu[1][kt], ZH, ZL);
      mmsplit(ayh[kt], ayl[kt], Bu[2][kt], NIH, NIL);
      mmsplit(ahh[kt], ahl[kt], Bv[0][kt], RH, RL);
      mmsplit(ahh[kt], ahl[kt], Bv[1][kt], ZH, ZL);
      mmsplit(ahh[kt], ahl[kt], Bv[2][kt], NHH, NHL);
    }
    #pragma unroll
    for (int rI = 0; rI < 4; rI++){
      float rv = sigmoidf_(RH[rI] + RL[rI] + bir + bhr);
      float zv = sigmoidf_(ZH[rI] + ZL[rI] + biz + bhz);
      float nv = tanhf_(NIH[rI] + NIL[rI] + bin + rv*(NHH[rI] + NHL[rI] + bhn));
      float hnew = (1.f - zv)*nv + zv*hold[rI];
      hold[rI] = hnew;
      unsigned short hb = f2bf(hnew);
      int node = q*4 + rI;
      h1hi[rb][node][d] = hb;
      h1lo[rb][node][d] = f2bf(hnew - bf2f(hb));
    }
  };

  __syncthreads();

  #pragma unroll 1
  for (int t = 0; t < 60; t++){
    if (isA){
      const int p  = t & 1;
      const int nb = p ^ 1;
      bf16x8 ah[2], al[2];
      #pragma unroll
      for (int kt = 0; kt < 2; kt++){
        ah[kt] = *(const bf16x8*)&h0hi[p][c][kt*32 + q*8];
        al[kt] = *(const bf16x8*)&h0lo[p][c][kt*32 + q*8];
      }
      bf16x8 axh = {}, axl = {};
      if (q == 0){
        axh = *(const bf16x8*)&xp_hi[c][t][0];
        axl = *(const bf16x8*)&xp_lo[c][t][0];
      }
      f32x4 RH = {0,0,0,0}, RL = {0,0,0,0};
      f32x4 ZH = {0,0,0,0}, ZL = {0,0,0,0};
      f32x4 NIH = {0,0,0,0}, NIL = {0,0,0,0};
      f32x4 NHH = {0,0,0,0}, NHL = {0,0,0,0};
      mmsplit(axh, axl, Bu[0][0], RH, RL);
      mmsplit(axh, axl, Bu[1][0], ZH, ZL);
      mmsplit(axh, axl, Bu[2][0], NIH, NIL);
      #pragma unroll
      for (int kt = 0; kt < 2; kt++){
        mmsplit(ah[kt], al[kt], Bv[0][kt], RH, RL);
        mmsplit(ah[kt], al[kt], Bv[1][kt], ZH, ZL);
        mmsplit(ah[kt], al[kt], Bv[2][kt], NHH, NHL);
      }
      #pragma unroll
      for (int rI = 0; rI < 4; rI++){
        float rv = sigmoidf_(RH[rI] + RL[rI] + bir + bhr);
        float zv = sigmoidf_(ZH[rI] + ZL[rI] + biz + bhz);
        float nv = tanhf_(NIH[rI] + NIL[rI] + bin + rv*(NHH[rI] + NHL[rI] + bhn));
        float hnew = (1.f - zv)*nv + zv*hold[rI];
        hold[rI] = hnew;
        unsigned short hb = f2bf(hnew);
        int node = q*4 + rI;
        h0hi[nb][node][d] = hb;
        h0lo[nb][node][d] = f2bf(hnew - bf2f(hb));
      }
    } else if (t > 0){
      stepB(t - 1);
    }
    __syncthreads();
  }

  if (!isA){
    stepB(59);
    #pragma unroll
    for (int rI = 0; rI < 4; rI++){
      int node = nbase + q*4 + rI;
      hfin[(size_t)node*64 + d] = hold[rI];
    }
  }
}

// ---- per-node scalars: a_h, c_h (3 heads), g = h·fcw[64:], p0 = h·fcw[:64]+fcb ----
// ac layout (rows of 4000): 0:a0 1:c0 2:a1 3:c1 4:a2 5:c2 6:g 7:p0
__global__ void ac_kernel(const float* __restrict__ hfin,
                          const float* __restrict__ W0h, const float* __restrict__ W1h,
                          const float* __restrict__ W2h,
                          const float* __restrict__ fcw, const float* __restrict__ fcb,
                          float* __restrict__ ac){
  int lane = threadIdx.x & 63;
  int node = blockIdx.x*4 + (threadIdx.x >> 6);
  float hv = hfin[(size_t)node*64 + lane];
  const float* Ws[3] = {W0h, W1h, W2h};
  #pragma unroll
  for (int h = 0; h < 3; h++){
    float pa = hv * Ws[h][lane];
    float pc = hv * Ws[h][64 + lane];
    #pragma unroll
    for (int m = 32; m >= 1; m >>= 1){
      pa += __shfl_xor(pa, m, 64);
      pc += __shfl_xor(pc, m, 64);
    }
    if (lane == 0){
      ac[(size_t)(2*h)*4000 + node]   = pa;
      ac[(size_t)(2*h+1)*4000 + node] = pc;
    }
  }
  float pg = hv * fcw[64 + lane];
  float pp = hv * fcw[lane];
  #pragma unroll
  for (int m = 32; m >= 1; m >>= 1){
    pg += __shfl_xor(pg, m, 64);
    pp += __shfl_xor(pp, m, 64);
  }
  if (lane == 0){
    ac[(size_t)6*4000 + node] = pg;
    ac[(size_t)7*4000 + node] = pp + fcb[0];
  }
}

// -------- single-pass fused attention: z_h = Σ exp(v), y_h = Σ exp(v)·g[j] --------
// pred[i] = p0[i] + (1/3) Σ_h y_h/z_h.  No LDS score buffer, no second/third pass.
__global__ __launch_bounds__(256, 4)
void attn2_kernel(const float* __restrict__ rel, const float* __restrict__ ac,
                  const float* __restrict__ b0p, const float* __restrict__ b1p,
                  const float* __restrict__ b2p, float* __restrict__ pred){
  __shared__ float red[4][12];

  const int tid  = threadIdx.x;
  const int lane = tid & 63;
  const int w    = tid >> 6;
  const int i0   = blockIdx.x * 2;
  const float bh[3] = {b0p[0], b1p[0], b2p[0]};

  const float* c0 = ac + (size_t)1*4000;
  const float* c1 = ac + (size_t)3*4000;
  const float* c2 = ac + (size_t)5*4000;
  const float* gv = ac + (size_t)6*4000;
  const float* p0 = ac + (size_t)7*4000;

  float ai[2][3];
  #pragma unroll
  for (int r = 0; r < 2; r++)
    #pragma unroll
    for (int h = 0; h < 3; h++)
      ai[r][h] = ac[(size_t)(2*h)*4000 + i0 + r];

  float z[2][3] = {{0.f,0.f,0.f},{0.f,0.f,0.f}};
  float y[2][3] = {{0.f,0.f,0.f},{0.f,0.f,0.f}};

  // single pass: stream rel once with depth-2 register prefetch
  {
    const size_t base0 = (size_t)i0*4000;
    const size_t base1 = (size_t)(i0+1)*4000;
    int j = tid;
    bool hv0 = (j < 4000);
    bool hv1 = (j + 256 < 4000);
    f4v a0, a1, a2, a3, b0, b1, b2, b3;
    if (hv0){
      const f4v* rp0 = (const f4v*)(rel + (base0 + j)*8);
      const f4v* rp1 = (const f4v*)(rel + (base1 + j)*8);
      a0 = __builtin_nontemporal_load(rp0);
      a1 = __builtin_nontemporal_load(rp0 + 1);
      a2 = __builtin_nontemporal_load(rp1);
      a3 = __builtin_nontemporal_load(rp1 + 1);
    }
    if (hv1){
      const f4v* rp0 = (const f4v*)(rel + (base0 + j + 256)*8);
      const f4v* rp1 = (const f4v*)(rel + (base1 + j + 256)*8);
      b0 = __builtin_nontemporal_load(rp0);
      b1 = __builtin_nontemporal_load(rp0 + 1);
      b2 = __builtin_nontemporal_load(rp1);
      b3 = __builtin_nontemporal_load(rp1 + 1);
    }
    while (hv0){
      int j2 = j + 512;
      bool hv2 = (j2 < 4000);
      f4v n0, n1, n2, n3;
      if (hv2){
        const f4v* rp0 = (const f4v*)(rel + (base0 + j2)*8);
        const f4v* rp1 = (const f4v*)(rel + (base1 + j2)*8);
        n0 = __builtin_nontemporal_load(rp0);
        n1 = __builtin_nontemporal_load(rp0 + 1);
        n2 = __builtin_nontemporal_load(rp1);
        n3 = __builtin_nontemporal_load(rp1 + 1);
      }
      float mk0 = a0[0]+a0[1]+a0[2]+a0[3] + a1[0]+a1[1]+a1[2]+a1[3];
      float mk1 = a2[0]+a2[1]+a2[2]+a2[3] + a3[0]+a3[1]+a3[2]+a3[3];
      float cv[3] = {c0[j], c1[j], c2[j]};
      float gj = gv[j];
      #pragma unroll
      for (int h = 0; h < 3; h++){
        float s0 = ai[0][h] + cv[h] + bh[h];
        float s1 = ai[1][h] + cv[h] + bh[h];
        float w0 = s0 > 0.f ? s0 : 0.01f*s0;
        float w1 = s1 > 0.f ? s1 : 0.01f*s1;
        float v0 = (mk0 == 0.f) ? -1e6f : mk0*w0;
        float v1 = (mk1 == 0.f) ? -1e6f : mk1*w1;
        float e0 = __expf(v0);
        float e1 = __expf(v1);
        z[0][h] += e0;  y[0][h] = fmaf(e0, gj, y[0][h]);
        z[1][h] += e1;  y[1][h] = fmaf(e1, gj, y[1][h]);
      }
      a0 = b0; a1 = b1; a2 = b2; a3 = b3;
      b0 = n0; b1 = n1; b2 = n2; b3 = n3;
      j += 256; hv0 = hv1; hv1 = hv2;
    }
  }

  // wave-reduce 12 (z,y) pairs, then cross-wave via tiny LDS
  #pragma unroll
  for (int r = 0; r < 2; r++)
    #pragma unroll
    for (int h = 0; h < 3; h++){
      float vz = z[r][h], vy = y[r][h];
      #pragma unroll
      for (int m = 32; m >= 1; m >>= 1){
        vz += __shfl_xor(vz, m, 64);
        vy += __shfl_xor(vy, m, 64);
      }
      if (lane == 0){
        red[w][(r*3 + h)*2 + 0] = vz;
        red[w][(r*3 + h)*2 + 1] = vy;
      }
    }
  __syncthreads();
  if (tid < 2){
    int r = tid;
    float acc = 0.f;
    #pragma unroll
    for (int h = 0; h < 3; h++){
      float zz = red[0][(r*3+h)*2] + red[1][(r*3+h)*2] + red[2][(r*3+h)*2] + red[3][(r*3+h)*2];
      float yy = red[0][(r*3+h)*2+1] + red[1][(r*3+h)*2+1] + red[2][(r*3+h)*2+1] + red[3][(r*3+h)*2+1];
      acc += yy / zz;
    }
    pred[i0 + r] = p0[i0 + r] + acc * (1.f/3.f);
  }
}

extern "C" void kernel_launch(void* const* d_in, const int* in_sizes, int n_in,
                              void* d_out, int out_size, void* d_ws, size_t ws_size,
                              hipStream_t stream) {
  const float* x    = (const float*)d_in[0];
  const float* rel  = (const float*)d_in[1];
  const float* Wih0 = (const float*)d_in[2];
  const float* Whh0 = (const float*)d_in[3];
  const float* bih0 = (const float*)d_in[4];
  const float* bhh0 = (const float*)d_in[5];
  const float* Wih1 = (const float*)d_in[6];
  const float* Whh1 = (const float*)d_in[7];
  const float* bih1 = (const float*)d_in[8];
  const float* bhh1 = (const float*)d_in[9];
  const float* W0   = (const float*)d_in[10];
  const float* b0   = (const float*)d_in[11];
  const float* W1   = (const float*)d_in[12];
  const float* b1   = (const float*)d_in[13];
  const float* W2   = (const float*)d_in[14];
  const float* b2   = (const float*)d_in[15];
  const float* fcw  = (const float*)d_in[16];
  const float* fcb  = (const float*)d_in[17];
  float* pred = (float*)d_out;
  float* hfin = (float*)d_ws;          // 4000*64 f32
  float* ac   = hfin + 4000*64;        // 8*4000 f32: a0,c0,a1,c1,a2,c2,g,p0

  gru_kernel<<<dim3(250), dim3(512), 0, stream>>>(x, Wih0, Whh0, bih0, bhh0,
                                                  Wih1, Whh1, bih1, bhh1, hfin);
  ac_kernel<<<dim3(1000), dim3(256), 0, stream>>>(hfin, W0, W1, W2, fcw, fcb, ac);
  attn2_kernel<<<dim3(2000), dim3(256), 0, stream>>>(rel, ac, b0, b1, b2, pred);
}

// Round 5
// 774.354 us; speedup vs baseline: 1.1324x; 1.0052x over previous
//
#include <hip/hip_runtime.h>

typedef __attribute__((ext_vector_type(8))) short bf16x8;
typedef __attribute__((ext_vector_type(4))) float f32x4;
typedef __attribute__((ext_vector_type(4))) float f4v;

__device__ __forceinline__ unsigned short f2bf(float f){
  unsigned u = __builtin_bit_cast(unsigned, f);
  u += 0x7FFFu + ((u >> 16) & 1u);
  return (unsigned short)(u >> 16);
}
__device__ __forceinline__ float bf2f(unsigned short b){
  unsigned u = ((unsigned)b) << 16;
  return __builtin_bit_cast(float, u);
}
__device__ __forceinline__ float sigmoidf_(float x){ return 1.f/(1.f + __expf(-x)); }
__device__ __forceinline__ float tanhf_(float x){
  float a = fabsf(x);
  float t = __expf(-2.f*a);
  float r = (1.f - t)/(1.f + t);
  return copysignf(r, x);
}

struct WF { bf16x8 hi, lo; };

// split-precision accumulate: hi-chain gets ah*Bhi, lo-chain gets al*Bhi + ah*Blo
__device__ __forceinline__ void mmsplit(bf16x8 ah, bf16x8 al, const WF& B,
                                        f32x4& Dh, f32x4& Dl){
  Dh = __builtin_amdgcn_mfma_f32_16x16x32_bf16(ah, B.hi, Dh, 0, 0, 0);
  Dl = __builtin_amdgcn_mfma_f32_16x16x32_bf16(al, B.hi, Dl, 0, 0, 0);
  Dl = __builtin_amdgcn_mfma_f32_16x16x32_bf16(ah, B.lo, Dl, 0, 0, 0);
}

__device__ __forceinline__ WF load_wf(const float* W, int ldk, int row, int k0, int kmax){
  WF f;
  #pragma unroll
  for (int j = 0; j < 8; j++){
    int k = k0 + j;
    float v = (k < kmax) ? W[row*ldk + k] : 0.f;
    unsigned short hb = f2bf(v);
    f.hi[j] = (short)hb;
    f.lo[j] = (short)f2bf(v - bf2f(hb));
  }
  return f;
}

// ---- GRU: 2 layers, split-wave skewed pipeline + fused ac epilogue ----
// waves 0-3 (A): layer 0 at step t; waves 4-7 (B): layer 1 at step t-1.
// Epilogue: final h for the block's 16 nodes is on-chip -> compute the 8
// per-node scalars (a0,c0,a1,c1,a2,c2,g,p0) directly; hfin/ac_kernel deleted.
__global__ __launch_bounds__(512, 2)
void gru_kernel(const float* __restrict__ x,
                const float* __restrict__ Wih0, const float* __restrict__ Whh0,
                const float* __restrict__ bih0, const float* __restrict__ bhh0,
                const float* __restrict__ Wih1, const float* __restrict__ Whh1,
                const float* __restrict__ bih1, const float* __restrict__ bhh1,
                const float* __restrict__ W0h, const float* __restrict__ W1h,
                const float* __restrict__ W2h,
                const float* __restrict__ fcw, const float* __restrict__ fcb,
                float* __restrict__ ac){
  __shared__ unsigned short xp_hi[16][60][8];
  __shared__ unsigned short xp_lo[16][60][8];
  __shared__ unsigned short h0hi[2][16][72], h0lo[2][16][72];
  __shared__ unsigned short h1hi[2][16][72], h1lo[2][16][72];
  __shared__ float hsh[16][64];

  const int tid  = threadIdx.x;
  const int lane = tid & 63;
  const int wv   = tid >> 6;          // 0..7
  const bool isA = (wv < 4);          // wave-uniform
  const int w    = wv & 3;
  const int c    = lane & 15;
  const int q    = lane >> 4;
  const int d    = w*16 + c;
  const int nbase = blockIdx.x * 16;

  for (int v = tid; v < 16*360; v += 512){
    int n = v / 360, rem = v % 360;
    int dd = rem / 60, tt = rem % 60;
    float f = x[(size_t)(nbase + n)*360 + rem];
    unsigned short hb = f2bf(f);
    xp_hi[n][tt][dd] = hb;
    xp_lo[n][tt][dd] = f2bf(f - bf2f(hb));
  }
  for (int v = tid; v < 16*60*2; v += 512){
    int n = v / 120, rem = v % 120;
    int tt = rem >> 1, dd = 6 + (rem & 1);
    xp_hi[n][tt][dd] = 0; xp_lo[n][tt][dd] = 0;
  }
  for (int v = tid; v < 2*16*72; v += 512){
    ((unsigned short*)h0hi)[v] = 0; ((unsigned short*)h0lo)[v] = 0;
    ((unsigned short*)h1hi)[v] = 0; ((unsigned short*)h1lo)[v] = 0;
  }

  const float* bib = isA ? bih0 : bih1;
  const float* bhb = isA ? bhh0 : bhh1;
  const float bir = bib[d], biz = bib[64+d], bin = bib[128+d];
  const float bhr = bhb[d], bhz = bhb[64+d], bhn = bhb[128+d];

  WF Bu[3][2], Bv[3][2];
  #pragma unroll
  for (int g = 0; g < 3; g++){
    int row = g*64 + d;
    if (isA){
      Bu[g][0] = load_wf(Wih0, 6, row, q*8, 6);
      Bu[g][1] = Bu[g][0];
      #pragma unroll
      for (int kt = 0; kt < 2; kt++)
        Bv[g][kt] = load_wf(Whh0, 64, row, kt*32 + q*8, 64);
    } else {
      #pragma unroll
      for (int kt = 0; kt < 2; kt++){
        Bu[g][kt] = load_wf(Wih1, 64, row, kt*32 + q*8, 64);
        Bv[g][kt] = load_wf(Whh1, 64, row, kt*32 + q*8, 64);
      }
    }
  }

  float hold[4] = {0,0,0,0};

  auto stepB = [&](int s){
    const int rb = (s + 1) & 1;
    const int sb = s & 1;
    bf16x8 ayh[2], ayl[2], ahh[2], ahl[2];
    #pragma unroll
    for (int kt = 0; kt < 2; kt++){
      ayh[kt] = *(const bf16x8*)&h0hi[rb][c][kt*32 + q*8];
      ayl[kt] = *(const bf16x8*)&h0lo[rb][c][kt*32 + q*8];
      ahh[kt] = *(const bf16x8*)&h1hi[sb][c][kt*32 + q*8];
      ahl[kt] = *(const bf16x8*)&h1lo[sb][c][kt*32 + q*8];
    }
    f32x4 RH = {0,0,0,0}, RL = {0,0,0,0};
    f32x4 ZH = {0,0,0,0}, ZL = {0,0,0,0};
    f32x4 NIH = {0,0,0,0}, NIL = {0,0,0,0};
    f32x4 NHH = {0,0,0,0}, NHL = {0,0,0,0};
    #pragma unroll
    for (int kt = 0; kt < 2; kt++){
      mmsplit(ayh[kt], ayl[kt], Bu[0][kt], RH, RL);
      mmsplit(ayh[kt], ayl[kt], Bu[1][kt], ZH, ZL);
      mmsplit(ayh[kt], ayl[kt], Bu[2][kt], NIH, NIL);
      mmsplit(ahh[kt], ahl[kt], Bv[0][kt], RH, RL);
      mmsplit(ahh[kt], ahl[kt], Bv[1][kt], ZH, ZL);
      mmsplit(ahh[kt], ahl[kt], Bv[2][kt], NHH, NHL);
    }
    #pragma unroll
    for (int rI = 0; rI < 4; rI++){
      float rv = sigmoidf_(RH[rI] + RL[rI] + bir + bhr);
      float zv = sigmoidf_(ZH[rI] + ZL[rI] + biz + bhz);
      float nv = tanhf_(NIH[rI] + NIL[rI] + bin + rv*(NHH[rI] + NHL[rI] + bhn));
      float hnew = (1.f - zv)*nv + zv*hold[rI];
      hold[rI] = hnew;
      unsigned short hb = f2bf(hnew);
      int node = q*4 + rI;
      h1hi[rb][node][d] = hb;
      h1lo[rb][node][d] = f2bf(hnew - bf2f(hb));
    }
  };

  __syncthreads();

  #pragma unroll 1
  for (int t = 0; t < 60; t++){
    if (isA){
      const int p  = t & 1;
      const int nb = p ^ 1;
      bf16x8 ah[2], al[2];
      #pragma unroll
      for (int kt = 0; kt < 2; kt++){
        ah[kt] = *(const bf16x8*)&h0hi[p][c][kt*32 + q*8];
        al[kt] = *(const bf16x8*)&h0lo[p][c][kt*32 + q*8];
      }
      bf16x8 axh = {}, axl = {};
      if (q == 0){
        axh = *(const bf16x8*)&xp_hi[c][t][0];
        axl = *(const bf16x8*)&xp_lo[c][t][0];
      }
      f32x4 RH = {0,0,0,0}, RL = {0,0,0,0};
      f32x4 ZH = {0,0,0,0}, ZL = {0,0,0,0};
      f32x4 NIH = {0,0,0,0}, NIL = {0,0,0,0};
      f32x4 NHH = {0,0,0,0}, NHL = {0,0,0,0};
      mmsplit(axh, axl, Bu[0][0], RH, RL);
      mmsplit(axh, axl, Bu[1][0], ZH, ZL);
      mmsplit(axh, axl, Bu[2][0], NIH, NIL);
      #pragma unroll
      for (int kt = 0; kt < 2; kt++){
        mmsplit(ah[kt], al[kt], Bv[0][kt], RH, RL);
        mmsplit(ah[kt], al[kt], Bv[1][kt], ZH, ZL);
        mmsplit(ah[kt], al[kt], Bv[2][kt], NHH, NHL);
      }
      #pragma unroll
      for (int rI = 0; rI < 4; rI++){
        float rv = sigmoidf_(RH[rI] + RL[rI] + bir + bhr);
        float zv = sigmoidf_(ZH[rI] + ZL[rI] + biz + bhz);
        float nv = tanhf_(NIH[rI] + NIL[rI] + bin + rv*(NHH[rI] + NHL[rI] + bhn));
        float hnew = (1.f - zv)*nv + zv*hold[rI];
        hold[rI] = hnew;
        unsigned short hb = f2bf(hnew);
        int node = q*4 + rI;
        h0hi[nb][node][d] = hb;
        h0lo[nb][node][d] = f2bf(hnew - bf2f(hb));
      }
    } else if (t > 0){
      stepB(t - 1);
    }
    __syncthreads();
  }

  if (!isA){
    stepB(59);
    #pragma unroll
    for (int rI = 0; rI < 4; rI++)
      hsh[q*4 + rI][d] = hold[rI];
  }
  __syncthreads();

  // fused ac epilogue: all 8 waves, 2 nodes each; same shfl ladder as old
  // ac_kernel -> bit-identical results.
  {
    const float w0a = W0h[lane], w0c = W0h[64 + lane];
    const float w1a = W1h[lane], w1c = W1h[64 + lane];
    const float w2a = W2h[lane], w2c = W2h[64 + lane];
    const float gw  = fcw[64 + lane], pw = fcw[lane];
    #pragma unroll
    for (int nn = 0; nn < 2; nn++){
      int n = wv*2 + nn;
      float hv = hsh[n][lane];
      float pa0 = hv*w0a, pc0 = hv*w0c;
      float pa1 = hv*w1a, pc1 = hv*w1c;
      float pa2 = hv*w2a, pc2 = hv*w2c;
      float pg  = hv*gw,  pp  = hv*pw;
      #pragma unroll
      for (int m = 32; m >= 1; m >>= 1){
        pa0 += __shfl_xor(pa0, m, 64); pc0 += __shfl_xor(pc0, m, 64);
        pa1 += __shfl_xor(pa1, m, 64); pc1 += __shfl_xor(pc1, m, 64);
        pa2 += __shfl_xor(pa2, m, 64); pc2 += __shfl_xor(pc2, m, 64);
        pg  += __shfl_xor(pg,  m, 64); pp  += __shfl_xor(pp,  m, 64);
      }
      if (lane == 0){
        size_t node = (size_t)(nbase + n);
        ac[0*4000 + node] = pa0; ac[1*4000 + node] = pc0;
        ac[2*4000 + node] = pa1; ac[3*4000 + node] = pc1;
        ac[4*4000 + node] = pa2; ac[5*4000 + node] = pc2;
        ac[6*4000 + node] = pg;  ac[7*4000 + node] = pp + fcb[0];
      }
    }
  }
}

// -------- single-pass fused attention: z_h = Σ exp(v), y_h = Σ exp(v)·g[j] --------
// pred[i] = p0[i] + (1/3) Σ_h y_h/z_h.
__global__ __launch_bounds__(256, 4)
void attn2_kernel(const float* __restrict__ rel, const float* __restrict__ ac,
                  const float* __restrict__ b0p, const float* __restrict__ b1p,
                  const float* __restrict__ b2p, float* __restrict__ pred){
  __shared__ float red[4][12];

  const int tid  = threadIdx.x;
  const int lane = tid & 63;
  const int w    = tid >> 6;
  const int i0   = blockIdx.x * 2;
  const float bh[3] = {b0p[0], b1p[0], b2p[0]};

  const float* c0 = ac + (size_t)1*4000;
  const float* c1 = ac + (size_t)3*4000;
  const float* c2 = ac + (size_t)5*4000;
  const float* gv = ac + (size_t)6*4000;
  const float* p0 = ac + (size_t)7*4000;

  float ai[2][3];
  #pragma unroll
  for (int r = 0; r < 2; r++)
    #pragma unroll
    for (int h = 0; h < 3; h++)
      ai[r][h] = ac[(size_t)(2*h)*4000 + i0 + r];

  float z[2][3] = {{0.f,0.f,0.f},{0.f,0.f,0.f}};
  float y[2][3] = {{0.f,0.f,0.f},{0.f,0.f,0.f}};

  // single pass: stream rel once with depth-2 register prefetch
  {
    const size_t base0 = (size_t)i0*4000;
    const size_t base1 = (size_t)(i0+1)*4000;
    int j = tid;
    bool hv0 = (j < 4000);
    bool hv1 = (j + 256 < 4000);
    f4v a0, a1, a2, a3, b0, b1, b2, b3;
    if (hv0){
      const f4v* rp0 = (const f4v*)(rel + (base0 + j)*8);
      const f4v* rp1 = (const f4v*)(rel + (base1 + j)*8);
      a0 = __builtin_nontemporal_load(rp0);
      a1 = __builtin_nontemporal_load(rp0 + 1);
      a2 = __builtin_nontemporal_load(rp1);
      a3 = __builtin_nontemporal_load(rp1 + 1);
    }
    if (hv1){
      const f4v* rp0 = (const f4v*)(rel + (base0 + j + 256)*8);
      const f4v* rp1 = (const f4v*)(rel + (base1 + j + 256)*8);
      b0 = __builtin_nontemporal_load(rp0);
      b1 = __builtin_nontemporal_load(rp0 + 1);
      b2 = __builtin_nontemporal_load(rp1);
      b3 = __builtin_nontemporal_load(rp1 + 1);
    }
    while (hv0){
      int j2 = j + 512;
      bool hv2 = (j2 < 4000);
      f4v n0, n1, n2, n3;
      if (hv2){
        const f4v* rp0 = (const f4v*)(rel + (base0 + j2)*8);
        const f4v* rp1 = (const f4v*)(rel + (base1 + j2)*8);
        n0 = __builtin_nontemporal_load(rp0);
        n1 = __builtin_nontemporal_load(rp0 + 1);
        n2 = __builtin_nontemporal_load(rp1);
        n3 = __builtin_nontemporal_load(rp1 + 1);
      }
      float mk0 = a0[0]+a0[1]+a0[2]+a0[3] + a1[0]+a1[1]+a1[2]+a1[3];
      float mk1 = a2[0]+a2[1]+a2[2]+a2[3] + a3[0]+a3[1]+a3[2]+a3[3];
      float cv[3] = {c0[j], c1[j], c2[j]};
      float gj = gv[j];
      #pragma unroll
      for (int h = 0; h < 3; h++){
        float s0 = ai[0][h] + cv[h] + bh[h];
        float s1 = ai[1][h] + cv[h] + bh[h];
        float w0 = s0 > 0.f ? s0 : 0.01f*s0;
        float w1 = s1 > 0.f ? s1 : 0.01f*s1;
        float v0 = (mk0 == 0.f) ? -1e6f : mk0*w0;
        float v1 = (mk1 == 0.f) ? -1e6f : mk1*w1;
        float e0 = __expf(v0);
        float e1 = __expf(v1);
        z[0][h] += e0;  y[0][h] = fmaf(e0, gj, y[0][h]);
        z[1][h] += e1;  y[1][h] = fmaf(e1, gj, y[1][h]);
      }
      a0 = b0; a1 = b1; a2 = b2; a3 = b3;
      b0 = n0; b1 = n1; b2 = n2; b3 = n3;
      j += 256; hv0 = hv1; hv1 = hv2;
    }
  }

  // wave-reduce 12 (z,y) pairs, then cross-wave via tiny LDS
  #pragma unroll
  for (int r = 0; r < 2; r++)
    #pragma unroll
    for (int h = 0; h < 3; h++){
      float vz = z[r][h], vy = y[r][h];
      #pragma unroll
      for (int m = 32; m >= 1; m >>= 1){
        vz += __shfl_xor(vz, m, 64);
        vy += __shfl_xor(vy, m, 64);
      }
      if (lane == 0){
        red[w][(r*3 + h)*2 + 0] = vz;
        red[w][(r*3 + h)*2 + 1] = vy;
      }
    }
  __syncthreads();
  if (tid < 2){
    int r = tid;
    float acc = 0.f;
    #pragma unroll
    for (int h = 0; h < 3; h++){
      float zz = red[0][(r*3+h)*2] + red[1][(r*3+h)*2] + red[2][(r*3+h)*2] + red[3][(r*3+h)*2];
      float yy = red[0][(r*3+h)*2+1] + red[1][(r*3+h)*2+1] + red[2][(r*3+h)*2+1] + red[3][(r*3+h)*2+1];
      acc += yy / zz;
    }
    pred[i0 + r] = p0[i0 + r] + acc * (1.f/3.f);
  }
}

extern "C" void kernel_launch(void* const* d_in, const int* in_sizes, int n_in,
                              void* d_out, int out_size, void* d_ws, size_t ws_size,
                              hipStream_t stream) {
  const float* x    = (const float*)d_in[0];
  const float* rel  = (const float*)d_in[1];
  const float* Wih0 = (const float*)d_in[2];
  const float* Whh0 = (const float*)d_in[3];
  const float* bih0 = (const float*)d_in[4];
  const float* bhh0 = (const float*)d_in[5];
  const float* Wih1 = (const float*)d_in[6];
  const float* Whh1 = (const float*)d_in[7];
  const float* bih1 = (const float*)d_in[8];
  const float* bhh1 = (const float*)d_in[9];
  const float* W0   = (const float*)d_in[10];
  const float* b0   = (const float*)d_in[11];
  const float* W1   = (const float*)d_in[12];
  const float* b1   = (const float*)d_in[13];
  const float* W2   = (const float*)d_in[14];
  const float* b2   = (const float*)d_in[15];
  const float* fcw  = (const float*)d_in[16];
  const float* fcb  = (const float*)d_in[17];
  float* pred = (float*)d_out;
  float* ac   = (float*)d_ws;          // 8*4000 f32: a0,c0,a1,c1,a2,c2,g,p0

  gru_kernel<<<dim3(250), dim3(512), 0, stream>>>(x, Wih0, Whh0, bih0, bhh0,
                                                  Wih1, Whh1, bih1, bhh1,
                                                  W0, W1, W2, fcw, fcb, ac);
  attn2_kernel<<<dim3(2000), dim3(256), 0, stream>>>(rel, ac, b0, b1, b2, pred);
}